// Round 10
// baseline (32.539 us; speedup 1.0000x reference)
//
#include <hip/hip_runtime.h>
#include <math.h>

#define BB 8
#define SS 64
#define NN 512
#define EE 32
#define IT 16

__device__ __forceinline__ unsigned short f2bf(float f) {
    union { float f; unsigned u; } v; v.f = f;
    unsigned r = v.u + 0x7fffu + ((v.u >> 16) & 1u);   // RTNE
    return (unsigned short)(r >> 16);
}
__device__ __forceinline__ float bflo(unsigned u) { return __uint_as_float(u << 16); }
__device__ __forceinline__ float bfhi(unsigned u) { return __uint_as_float(u & 0xffff0000u); }

__device__ __forceinline__ float qsum(float v) {      // sum over 4-lane quad (VALU pipe)
    v += __int_as_float(__builtin_amdgcn_mov_dpp(__float_as_int(v), 0xB1, 0xF, 0xF, true));
    v += __int_as_float(__builtin_amdgcn_mov_dpp(__float_as_int(v), 0x4E, 0xF, 0xF, true));
    return v;
}

// proj: tip[b][e][n] fp32 = ti'+b_w; tjb[b][e][n] bf16-packed = tj  (layout B,E,N)
//       cip[b][n] = sum_e Wa[e]*ti'[n][e];  djp[b][n] = sum_e Wa[e]*tj[n][e]
__global__ __launch_bounds__(128) void proj_kernel(
    const float* __restrict__ x, const float* __restrict__ W,
    const float* __restrict__ b_w, const float* __restrict__ Wa,
    float* __restrict__ tip, unsigned short* __restrict__ tjb,
    float* __restrict__ cip, float* __restrict__ djp)
{
    __shared__ float sW[SS][65];
    const int t = threadIdx.x;
    const int wg = ((blockIdx.x & 7) << 6) | (blockIdx.x >> 3);  // XCD swizzle (512=8*64)
    const int b = wg >> 6;
    const int n0 = (wg & 63) << 3;

#pragma unroll
    for (int r = 0; r < 8; ++r) {   // stage W (4096 floats) as [s][eo]
        int idx = r * 512 + t * 4;
        float4 w4 = *(const float4*)(W + idx);
        int e = idx >> 7;
        int sp = idx & 127;
        int eo = ((sp >> 6) << 5) | e;   // 0..31 ti, 32..63 tj
        int s0 = sp & 63;
        sW[s0 + 0][eo] = w4.x;
        sW[s0 + 1][eo] = w4.y;
        sW[s0 + 2][eo] = w4.z;
        sW[s0 + 3][eo] = w4.w;
    }
    __syncthreads();

    const int eo = t & 63;
    const int ng = t >> 6;               // 0/1
    const float* xb = x + (size_t)b * SS * NN + n0 + (ng << 2);
    float a0 = 0.f, a1 = 0.f, a2 = 0.f, a3 = 0.f;
#pragma unroll 8
    for (int s = 0; s < SS; ++s) {
        float wv = sW[s][eo];                               // conflict-free
        float4 xv = *(const float4*)(xb + (size_t)s * NN);  // wave-uniform bcast
        a0 = fmaf(wv, xv.x, a0);
        a1 = fmaf(wv, xv.y, a1);
        a2 = fmaf(wv, xv.z, a2);
        a3 = fmaf(wv, xv.w, a3);
    }
    const int e = eo & 31;
    const bool isI = eo < EE;
    if (isI) {
        float bias = b_w[e];
        a0 += bias; a1 += bias; a2 += bias; a3 += bias;
        *(float4*)(tip + ((size_t)(b * EE + e)) * NN + n0 + (ng << 2)) =
            make_float4(a0, a1, a2, a3);
    } else {
        unsigned u0 = f2bf(a0) | ((unsigned)f2bf(a1) << 16);
        unsigned u1 = f2bf(a2) | ((unsigned)f2bf(a3) << 16);
        *(uint2*)(tjb + ((size_t)(b * EE + e)) * NN + n0 + (ng << 2)) =
            make_uint2(u0, u1);
    }

    // rank-1 terms: reduce wa*val over each 32-lane half (xor<32 keeps halves apart)
    float wa = Wa[e];
    float r0 = wa * a0, r1 = wa * a1, r2 = wa * a2, r3 = wa * a3;
#pragma unroll
    for (int off = 1; off <= 16; off <<= 1) {
        r0 += __shfl_xor(r0, off);
        r1 += __shfl_xor(r1, off);
        r2 += __shfl_xor(r2, off);
        r3 += __shfl_xor(r3, off);
    }
    if (eo == 0)
        *(float4*)(cip + (size_t)b * NN + n0 + (ng << 2)) = make_float4(r0, r1, r2, r3);
    if (eo == 32)
        *(float4*)(djp + (size_t)b * NN + n0 + (ng << 2)) = make_float4(r0, r1, r2, r3);
}

// attn: block = (b, 16-i tile), 1024 threads (16 waves = 4/SIMD), grid 256.
// (1024,4) => 128-VGPR cap (proven spill-free for this PV tile in R9).
// LDS ~108 KB, 1 block/CU.
__global__ __launch_bounds__(1024, 4) void attn_kernel(
    const float* __restrict__ x,
    const float* __restrict__ tip,
    const unsigned short* __restrict__ tjb,
    const float* __restrict__ cip,
    const float* __restrict__ djp,
    const float* __restrict__ Wa,
    float* __restrict__ out0,
    float* __restrict__ out1)
{
    __shared__ __align__(16) unsigned scT[NN * 12];        // 24KB: row j = 8 u32 (16 bf16) + pad
    __shared__ __align__(16) float hp[16 * SS * 20];       // 80KB PV partials [w16][s][20]
    __shared__ __align__(16) float s_tiT[IT][36];          // [i][e] fp32
    __shared__ __align__(16) float red[16][IT];
    __shared__ float s_inv[IT];

    const int t = threadIdx.x;
    const int wg = ((blockIdx.x & 7) << 5) | (blockIdx.x >> 3);  // XCD swizzle (256=8*32)
    const int b = wg >> 5;
    const int i0 = (wg & 31) << 4;
    const int lane = t & 63;
    const int w16 = t >> 6;

    if (t < 256) {                       // stage ti (16 i x 32 e individually? 512 elems)
        int i = t & 15, e = t >> 4;
        s_tiT[i][e] = tip[((size_t)(b * EE + e)) * NN + i0 + i];
        if (t < IT * EE - 256) {}        // (single pass covers 256 of 512; second below)
    }
    if (t >= 256 && t < 512) {
        int tt = t;                      // covers e 16..31
        int i = tt & 15, e = tt >> 4;
        s_tiT[i][e] = tip[((size_t)(b * EE + e)) * NN + i0 + i];
    }
    __syncthreads();

    // ---- scores: thread owns i-pair {2ip,2ip+1} x 4 j; tj from L2 (bf16) ----
    const int ip = t & 7;
    const int jc = t >> 3;               // 0..127
    const int j0 = jc << 2;              // 4 j
    const int ia = 2 * ip, ib2 = 2 * ip + 1;

    float rti0[EE], rti1[EE];
#pragma unroll
    for (int q = 0; q < 8; ++q) {
        float4 v = *(const float4*)&s_tiT[ia][q << 2];
        rti0[4 * q + 0] = v.x; rti0[4 * q + 1] = v.y;
        rti0[4 * q + 2] = v.z; rti0[4 * q + 3] = v.w;
        float4 u = *(const float4*)&s_tiT[ib2][q << 2];
        rti1[4 * q + 0] = u.x; rti1[4 * q + 1] = u.y;
        rti1[4 * q + 2] = u.z; rti1[4 * q + 3] = u.w;
    }

    float acc0[4], acc1[4];
#pragma unroll
    for (int k = 0; k < 4; ++k) { acc0[k] = 0.f; acc1[k] = 0.f; }

    const unsigned short* tjbb = tjb + (size_t)b * EE * NN + j0;
#pragma unroll
    for (int e = 0; e < EE; ++e) {
        uint2 d = *(const uint2*)(tjbb + (size_t)e * NN);   // 4 bf16 from L2
        float wa = Wa[e];                                   // uniform s_load
        float t0 = rti0[e], t1 = rti1[e];
        float tjf[4];
        tjf[0] = bflo(d.x); tjf[1] = bfhi(d.x);
        tjf[2] = bflo(d.y); tjf[3] = bfhi(d.y);
#pragma unroll
        for (int k = 0; k < 4; ++k) {
            acc0[k] = fmaf(fabsf(t0 + tjf[k]), wa, acc0[k]);   // |p| input-mod
            acc1[k] = fmaf(fabsf(t1 + tjf[k]), wa, acc1[k]);
        }
    }

    // epilogue: sc = 0.4*acc + 0.6*(ci + dj); no-max softmax (|sc| small, N(0,1) data)
    float4 dj4 = *(const float4*)(djp + (size_t)b * NN + j0);
    float dj[4] = {dj4.x, dj4.y, dj4.z, dj4.w};
    float c0 = cip[(size_t)b * NN + i0 + ia];
    float c1 = cip[(size_t)b * NN + i0 + ib2];
    float pr0[4], pr1[4];
#pragma unroll
    for (int k = 0; k < 4; ++k) {
        pr0[k] = __expf(fmaf(0.4f, acc0[k], 0.6f * (c0 + dj[k])));
        pr1[k] = __expf(fmaf(0.4f, acc1[k], 0.6f * (c1 + dj[k])));
    }

    // write scT: row j, slot ip = bf16 pair (i=2ip,2ip+1)
#pragma unroll
    for (int k = 0; k < 4; ++k)
        scT[(j0 + k) * 12 + ip] = f2bf(pr0[k]) | ((unsigned)f2bf(pr1[k]) << 16);

    // ---- softmax denominators ----
    float rs0 = pr0[0] + pr0[1] + pr0[2] + pr0[3];
    float rs1 = pr1[0] + pr1[1] + pr1[2] + pr1[3];
#pragma unroll
    for (int off = 8; off <= 32; off <<= 1) {
        rs0 += __shfl_xor(rs0, off);
        rs1 += __shfl_xor(rs1, off);
    }
    if (lane < 8) { red[w16][2 * lane] = rs0; red[w16][2 * lane + 1] = rs1; }
    __syncthreads();
    if (t < IT) {
        float S = 0.f;
#pragma unroll
        for (int ww = 0; ww < 16; ++ww) S += red[ww][t];
        s_inv[t] = 1.0f / S;
    }
    __syncthreads();                                     // s_inv + scT visible

    // ---- attention rows (fp32 pr, 16B/thread/row) ----
    {
        float v0 = s_inv[ia], v1 = s_inv[ib2];
        *(float4*)(out1 + ((size_t)(b * NN + i0 + ia)) * NN + j0) =
            make_float4(pr0[0]*v0, pr0[1]*v0, pr0[2]*v0, pr0[3]*v0);
        *(float4*)(out1 + ((size_t)(b * NN + i0 + ib2)) * NN + j0) =
            make_float4(pr1[0]*v1, pr1[1]*v1, pr1[2]*v1, pr1[3]*v1);
    }

    // ---- PV: wave w16 owns j in [w16*32, w16*32+32); lane=(jw,sq,ih) ----
    const int jw = t & 3;
    const int sq = (t >> 2) & 7;
    const int ih = (t >> 5) & 1;
    float pacc[8][8];
#pragma unroll
    for (int r = 0; r < 8; ++r)
#pragma unroll
        for (int c = 0; c < 8; ++c) pacc[r][c] = 0.f;

    const float* xbb = x + (size_t)b * SS * NN;
#pragma unroll
    for (int uu = 0; uu < 2; ++uu) {
        const int jb = (w16 << 5) + (uu << 4) + (jw << 2);
        float xq[8][4];
#pragma unroll
        for (int r = 0; r < 8; ++r) {
            float4 xv = *(const float4*)(xbb + (size_t)(sq + 8 * r) * NN + jb);
            xq[r][0] = xv.x; xq[r][1] = xv.y; xq[r][2] = xv.z; xq[r][3] = xv.w;
        }
#pragma unroll
        for (int v = 0; v < 4; ++v) {
            uint4 dd = *(const uint4*)&scT[(jb + v) * 12 + (ih << 2)];  // 2-way banks
            float ps[8];
            ps[0] = bflo(dd.x); ps[1] = bfhi(dd.x);
            ps[2] = bflo(dd.y); ps[3] = bfhi(dd.y);
            ps[4] = bflo(dd.z); ps[5] = bfhi(dd.z);
            ps[6] = bflo(dd.w); ps[7] = bfhi(dd.w);
#pragma unroll
            for (int r = 0; r < 8; ++r) {
                float xv = xq[r][v];
#pragma unroll
                for (int c = 0; c < 8; ++c)
                    pacc[r][c] = fmaf(xv, ps[c], pacc[r][c]);
            }
        }
    }

    // 4-lane jw reduction on VALU pipe (DPP)
#pragma unroll
    for (int r = 0; r < 8; ++r)
#pragma unroll
        for (int c = 0; c < 8; ++c) pacc[r][c] = qsum(pacc[r][c]);

    if (jw == 0) {
#pragma unroll
        for (int r = 0; r < 8; ++r) {
            int s = sq + 8 * r;
            float* hq = &hp[(w16 * SS + s) * 20 + ih * 8];
            *(float4*)(hq)     = make_float4(pacc[r][0], pacc[r][1], pacc[r][2], pacc[r][3]);
            *(float4*)(hq + 4) = make_float4(pacc[r][4], pacc[r][5], pacc[r][6], pacc[r][7]);
        }
    }
    __syncthreads();

    // ---- final: sum 16 wave-partials, scale, sigmoid, store (one pass) ----
    {
        int i = t & 15, s = t >> 4;       // 1024 = 64 s x 16 i
        float h = 0.f;
#pragma unroll
        for (int ww = 0; ww < 16; ++ww) h += hp[(ww * SS + s) * 20 + i];
        h *= s_inv[i];
        out0[((size_t)(b * SS + s)) * NN + i0 + i] = 1.0f / (1.0f + __expf(-h));
    }
}

extern "C" void kernel_launch(void* const* d_in, const int* in_sizes, int n_in,
                              void* d_out, int out_size, void* d_ws, size_t ws_size,
                              hipStream_t stream) {
    const float* x   = (const float*)d_in[0];
    const float* W   = (const float*)d_in[1];
    const float* b_w = (const float*)d_in[2];
    const float* Wa  = (const float*)d_in[3];

    float* out0 = (float*)d_out;                         // (B,S,N)
    float* out1 = (float*)d_out + (size_t)BB * SS * NN;  // (B,N,N)

    float* tip = (float*)d_ws;                                   // (B,E,N) fp32
    unsigned short* tjb = (unsigned short*)(tip + (size_t)BB * EE * NN);  // (B,E,N) bf16
    float* cip = (float*)(tjb + (size_t)BB * EE * NN);           // (B,N)
    float* djp = cip + (size_t)BB * NN;                          // (B,N)

    proj_kernel<<<BB * (NN / 8), 128, 0, stream>>>(x, W, b_w, Wa, tip, tjb, cip, djp);
    attn_kernel<<<BB * (NN / IT), 1024, 0, stream>>>(x, tip, tjb, cip, djp, Wa, out0, out1);
}

// Round 11
// 20.384 us; speedup vs baseline: 1.5963x; 1.5963x over previous
//
#include <hip/hip_runtime.h>
#include <math.h>

#define BB 8
#define SS 64
#define NN 512
#define EE 32
#define IT 16

typedef __attribute__((ext_vector_type(8))) short short8v;   // 8 bf16 (4 VGPRs)
typedef __attribute__((ext_vector_type(4))) float f32x4;

__device__ __forceinline__ unsigned short f2bf(float f) {
    union { float f; unsigned u; } v; v.f = f;
    unsigned r = v.u + 0x7fffu + ((v.u >> 16) & 1u);   // RTNE
    return (unsigned short)(r >> 16);
}
__device__ __forceinline__ float bflo(unsigned u) { return __uint_as_float(u << 16); }
__device__ __forceinline__ float bfhi(unsigned u) { return __uint_as_float(u & 0xffff0000u); }
// truncate-pack two fp32 into packed bf16x2 (cheap, used only for x in PV)
__device__ __forceinline__ unsigned packtr(float lo, float hi) {
    return (__float_as_uint(hi) & 0xffff0000u) | (__float_as_uint(lo) >> 16);
}

// proj: tip[b][e][n] fp32 = ti'+b_w; tjb[b][e][n] bf16-packed = tj  (layout B,E,N)
//       cip[b][n] = sum_e Wa[e]*ti'[n][e];  djp[b][n] = sum_e Wa[e]*tj[n][e]
__global__ __launch_bounds__(128) void proj_kernel(
    const float* __restrict__ x, const float* __restrict__ W,
    const float* __restrict__ b_w, const float* __restrict__ Wa,
    float* __restrict__ tip, unsigned short* __restrict__ tjb,
    float* __restrict__ cip, float* __restrict__ djp)
{
    __shared__ float sW[SS][65];
    const int t = threadIdx.x;
    const int wg = ((blockIdx.x & 7) << 6) | (blockIdx.x >> 3);  // XCD swizzle (512=8*64)
    const int b = wg >> 6;
    const int n0 = (wg & 63) << 3;

#pragma unroll
    for (int r = 0; r < 8; ++r) {   // stage W (4096 floats) as [s][eo]
        int idx = r * 512 + t * 4;
        float4 w4 = *(const float4*)(W + idx);
        int e = idx >> 7;
        int sp = idx & 127;
        int eo = ((sp >> 6) << 5) | e;   // 0..31 ti, 32..63 tj
        int s0 = sp & 63;
        sW[s0 + 0][eo] = w4.x;
        sW[s0 + 1][eo] = w4.y;
        sW[s0 + 2][eo] = w4.z;
        sW[s0 + 3][eo] = w4.w;
    }
    __syncthreads();

    const int eo = t & 63;
    const int ng = t >> 6;               // 0/1
    const float* xb = x + (size_t)b * SS * NN + n0 + (ng << 2);
    float a0 = 0.f, a1 = 0.f, a2 = 0.f, a3 = 0.f;
#pragma unroll 8
    for (int s = 0; s < SS; ++s) {
        float wv = sW[s][eo];                               // conflict-free
        float4 xv = *(const float4*)(xb + (size_t)s * NN);  // wave-uniform bcast
        a0 = fmaf(wv, xv.x, a0);
        a1 = fmaf(wv, xv.y, a1);
        a2 = fmaf(wv, xv.z, a2);
        a3 = fmaf(wv, xv.w, a3);
    }
    const int e = eo & 31;
    const bool isI = eo < EE;
    if (isI) {
        float bias = b_w[e];
        a0 += bias; a1 += bias; a2 += bias; a3 += bias;
        *(float4*)(tip + ((size_t)(b * EE + e)) * NN + n0 + (ng << 2)) =
            make_float4(a0, a1, a2, a3);
    } else {
        unsigned u0 = f2bf(a0) | ((unsigned)f2bf(a1) << 16);
        unsigned u1 = f2bf(a2) | ((unsigned)f2bf(a3) << 16);
        *(uint2*)(tjb + ((size_t)(b * EE + e)) * NN + n0 + (ng << 2)) =
            make_uint2(u0, u1);
    }

    // rank-1 terms: reduce wa*val over each 32-lane half (xor<32 keeps halves apart)
    float wa = Wa[e];
    float r0 = wa * a0, r1 = wa * a1, r2 = wa * a2, r3 = wa * a3;
#pragma unroll
    for (int off = 1; off <= 16; off <<= 1) {
        r0 += __shfl_xor(r0, off);
        r1 += __shfl_xor(r1, off);
        r2 += __shfl_xor(r2, off);
        r3 += __shfl_xor(r3, off);
    }
    if (eo == 0)
        *(float4*)(cip + (size_t)b * NN + n0 + (ng << 2)) = make_float4(r0, r1, r2, r3);
    if (eo == 32)
        *(float4*)(djp + (size_t)b * NN + n0 + (ng << 2)) = make_float4(r0, r1, r2, r3);
}

// attn: block = (b, 16-i tile), 512 threads (8 waves), grid 256. LDS ~61 KB.
// (512,2): 128-VGPR regime. NEVER (512,4): 64-cap => guaranteed spill (R5/R8).
// R11 change vs R9: PV phase -> MFMA (16x16x32 bf16), scT -> i-major prT.
__global__ __launch_bounds__(512, 2) void attn_kernel(
    const float* __restrict__ x,
    const float* __restrict__ tip,
    const unsigned short* __restrict__ tjb,
    const float* __restrict__ cip,
    const float* __restrict__ djp,
    const float* __restrict__ Wa,
    float* __restrict__ out0,
    float* __restrict__ out1)
{
    __shared__ __align__(16) unsigned short stj[EE * NN];     // 32KB bf16 tj
    __shared__ __align__(16) unsigned short prT[IT * 520];    // 16.6KB bf16 pr, i-major, pad 8
    __shared__ __align__(16) float s_tiT[IT][36];             // [i][e] fp32
    __shared__ __align__(16) float hp[2][SS][17];             // 8.7KB: K-half partials of h
    __shared__ __align__(16) float red[8][IT];
    __shared__ float s_inv[IT];

    const int t = threadIdx.x;
    const int wg = ((blockIdx.x & 7) << 5) | (blockIdx.x >> 3);  // XCD swizzle (256=8*32)
    const int b = wg >> 5;
    const int i0 = (wg & 31) << 4;
    const int lane = t & 63;
    const int w = t >> 6;

    // ---- stage ti (fp32) and tj (bf16) ----
    {
        int i = t & 15, e = t >> 4;
        s_tiT[i][e] = tip[((size_t)(b * EE + e)) * NN + i0 + i];
    }
    {
        const uint4* src = (const uint4*)(tjb + (size_t)b * EE * NN);
        uint4* dst = (uint4*)stj;
#pragma unroll
        for (int r = 0; r < 4; ++r) dst[r * 512 + t] = src[r * 512 + t];
    }
    __syncthreads();

    // ---- scores: thread owns i in {2ip,2ip+1}, j in [jc*8, jc*8+8) ----
    const int ip = t & 7;
    const int jc = t >> 3;          // 0..63
    const int j0 = jc << 3;
    const int ia = 2 * ip, ib2 = 2 * ip + 1;

    float rti0[EE], rti1[EE];
#pragma unroll
    for (int q = 0; q < 8; ++q) {
        float4 v = *(const float4*)&s_tiT[ia][q << 2];
        rti0[4 * q + 0] = v.x; rti0[4 * q + 1] = v.y;
        rti0[4 * q + 2] = v.z; rti0[4 * q + 3] = v.w;
        float4 u = *(const float4*)&s_tiT[ib2][q << 2];
        rti1[4 * q + 0] = u.x; rti1[4 * q + 1] = u.y;
        rti1[4 * q + 2] = u.z; rti1[4 * q + 3] = u.w;
    }

    float acc0[8], acc1[8];
#pragma unroll
    for (int k = 0; k < 8; ++k) { acc0[k] = 0.f; acc1[k] = 0.f; }

#pragma unroll
    for (int e = 0; e < EE; ++e) {
        uint4 d = *(const uint4*)&stj[e * NN + j0];      // 8 bf16, conflict-free b128
        float wa = Wa[e];                                // uniform s_load
        float t0 = rti0[e], t1 = rti1[e];
        float tjf[8];
        tjf[0] = bflo(d.x); tjf[1] = bfhi(d.x);
        tjf[2] = bflo(d.y); tjf[3] = bfhi(d.y);
        tjf[4] = bflo(d.z); tjf[5] = bfhi(d.z);
        tjf[6] = bflo(d.w); tjf[7] = bfhi(d.w);
#pragma unroll
        for (int k = 0; k < 8; ++k) {
            acc0[k] = fmaf(fabsf(t0 + tjf[k]), wa, acc0[k]);   // |p| input-mod
            acc1[k] = fmaf(fabsf(t1 + tjf[k]), wa, acc1[k]);
        }
    }

    // epilogue: sc = 0.4*acc + 0.6*(ci + dj); no-max softmax (|sc| small, N(0,1) data)
    float dj8[8];
    {
        float4 d0 = *(const float4*)(djp + (size_t)b * NN + j0);
        float4 d1 = *(const float4*)(djp + (size_t)b * NN + j0 + 4);
        dj8[0] = d0.x; dj8[1] = d0.y; dj8[2] = d0.z; dj8[3] = d0.w;
        dj8[4] = d1.x; dj8[5] = d1.y; dj8[6] = d1.z; dj8[7] = d1.w;
    }
    float c0 = cip[(size_t)b * NN + i0 + ia];
    float c1 = cip[(size_t)b * NN + i0 + ib2];
    float pr0[8], pr1[8];
#pragma unroll
    for (int k = 0; k < 8; ++k) {
        pr0[k] = __expf(fmaf(0.4f, acc0[k], 0.6f * (c0 + dj8[k])));
        pr1[k] = __expf(fmaf(0.4f, acc1[k], 0.6f * (c1 + dj8[k])));
    }

    // write prT (i-major, RTNE bf16): rows ia and ib2, cols j0..j0+8 (one b128 each)
    {
        uint4 pa, pb;
        pa.x = f2bf(pr0[0]) | ((unsigned)f2bf(pr0[1]) << 16);
        pa.y = f2bf(pr0[2]) | ((unsigned)f2bf(pr0[3]) << 16);
        pa.z = f2bf(pr0[4]) | ((unsigned)f2bf(pr0[5]) << 16);
        pa.w = f2bf(pr0[6]) | ((unsigned)f2bf(pr0[7]) << 16);
        pb.x = f2bf(pr1[0]) | ((unsigned)f2bf(pr1[1]) << 16);
        pb.y = f2bf(pr1[2]) | ((unsigned)f2bf(pr1[3]) << 16);
        pb.z = f2bf(pr1[4]) | ((unsigned)f2bf(pr1[5]) << 16);
        pb.w = f2bf(pr1[6]) | ((unsigned)f2bf(pr1[7]) << 16);
        *(uint4*)&prT[ia * 520 + j0]  = pa;   // pad-520 => 2-way banks (free)
        *(uint4*)&prT[ib2 * 520 + j0] = pb;
    }

    // ---- softmax denominators: in-thread sum + shuffle + cross-wave ----
    float rs0 = 0.f, rs1 = 0.f;
#pragma unroll
    for (int k = 0; k < 8; ++k) { rs0 += pr0[k]; rs1 += pr1[k]; }
#pragma unroll
    for (int off = 8; off <= 32; off <<= 1) {
        rs0 += __shfl_xor(rs0, off);
        rs1 += __shfl_xor(rs1, off);
    }
    if (lane < 8) { red[w][2 * lane] = rs0; red[w][2 * lane + 1] = rs1; }
    __syncthreads();
    if (t < IT) {
        float S = 0.f;
#pragma unroll
        for (int ww = 0; ww < 8; ++ww) S += red[ww][t];
        s_inv[t] = 1.0f / S;
    }
    __syncthreads();                                     // s_inv + prT visible

    // ---- attention rows (fp32 pr, coalesced 32B/thread) ----
    {
        float v0 = s_inv[ia], v1 = s_inv[ib2];
        float* r0p = out1 + ((size_t)(b * NN + i0 + ia)) * NN + j0;
        float* r1p = out1 + ((size_t)(b * NN + i0 + ib2)) * NN + j0;
        *(float4*)(r0p)     = make_float4(pr0[0]*v0, pr0[1]*v0, pr0[2]*v0, pr0[3]*v0);
        *(float4*)(r0p + 4) = make_float4(pr0[4]*v0, pr0[5]*v0, pr0[6]*v0, pr0[7]*v0);
        *(float4*)(r1p)     = make_float4(pr1[0]*v1, pr1[1]*v1, pr1[2]*v1, pr1[3]*v1);
        *(float4*)(r1p + 4) = make_float4(pr1[4]*v1, pr1[5]*v1, pr1[6]*v1, pr1[7]*v1);
    }

    // ---- PV via MFMA: h[s][i] = sum_j x[s][j]*pr[i][j] ----
    // wave w: M-tile mt = w&3 (16 s), K-half kh = w>>2 (256 j). 8 MFMA/wave.
    // A (16x32) = x rows (fp32->bf16 truncate-pack); B (32x16) = prT[i][k..k+8].
    {
        const int mt = w & 3;
        const int kh = w >> 2;
        const int lm = lane & 15;          // A-row (s in tile) / B-col (i)
        const int ko = lane >> 4;          // k-octet selector
        const float* xrow = x + ((size_t)(b * SS + mt * 16 + lm)) * NN;

        f32x4 acc = {0.f, 0.f, 0.f, 0.f};
#pragma unroll
        for (int st = 0; st < 8; ++st) {
            const int j = kh * 256 + st * 32 + ko * 8;
            float4 xa = *(const float4*)(xrow + j);
            float4 xb2 = *(const float4*)(xrow + j + 4);
            union { unsigned u[4]; short8v v; } af;
            af.u[0] = packtr(xa.x, xa.y);
            af.u[1] = packtr(xa.z, xa.w);
            af.u[2] = packtr(xb2.x, xb2.y);
            af.u[3] = packtr(xb2.z, xb2.w);
            short8v bf = *(const short8v*)&prT[lm * 520 + j];   // 2-way banks
            acc = __builtin_amdgcn_mfma_f32_16x16x32_bf16(af.v, bf, acc, 0, 0, 0);
        }
        // D layout: col i = lane&15, row = (lane>>4)*4 + reg  [guide m89/m91]
#pragma unroll
        for (int r = 0; r < 4; ++r) {
            int s = mt * 16 + (lane >> 4) * 4 + r;
            hp[kh][s][lm] = acc[r];
        }
    }
    __syncthreads();

    // ---- final: combine 2 K-half partials, scale, sigmoid, store ----
    {
        int i = t & 15, sb = t >> 4;       // 512 = 32 s x 16 i
        float vi = s_inv[i];
#pragma unroll
        for (int rr = 0; rr < 2; ++rr) {
            int s = sb + 32 * rr;
            float h = (hp[0][s][i] + hp[1][s][i]) * vi;
            out0[((size_t)(b * SS + s)) * NN + i0 + i] = 1.0f / (1.0f + __expf(-h));
        }
    }
}

extern "C" void kernel_launch(void* const* d_in, const int* in_sizes, int n_in,
                              void* d_out, int out_size, void* d_ws, size_t ws_size,
                              hipStream_t stream) {
    const float* x   = (const float*)d_in[0];
    const float* W   = (const float*)d_in[1];
    const float* b_w = (const float*)d_in[2];
    const float* Wa  = (const float*)d_in[3];

    float* out0 = (float*)d_out;                         // (B,S,N)
    float* out1 = (float*)d_out + (size_t)BB * SS * NN;  // (B,N,N)

    float* tip = (float*)d_ws;                                   // (B,E,N) fp32
    unsigned short* tjb = (unsigned short*)(tip + (size_t)BB * EE * NN);  // (B,E,N) bf16
    float* cip = (float*)(tjb + (size_t)BB * EE * NN);           // (B,N)
    float* djp = cip + (size_t)BB * NN;                          // (B,N)

    proj_kernel<<<BB * (NN / 8), 128, 0, stream>>>(x, W, b_w, Wa, tip, tjb, cip, djp);
    attn_kernel<<<BB * (NN / IT), 512, 0, stream>>>(x, tip, tjb, cip, djp, Wa, out0, out1);
}